// Round 12
// baseline (344.359 us; speedup 1.0000x reference)
//
#include <hip/hip_runtime.h>

// ---------------------------------------------------------------------------
// Hetero-SAGE edge classifier.
//  Round-12: (1) tobf16 piggyback moved from scatter launch to hist launch
//  (hist is latency-bound; conversion needs only raw inputs) -> scatter
//  critical chain shrinks. (2) m-side gather unroll-8 (template U) -> 64
//  outstanding rows/wave on deg-40 segments. (3) int4 edge reads in hist/
//  scatter (8 contiguous edges/thread; count/cursor semantics order-free).
//  (4) NT output stores in edge_mlp. Rest as R11.
// ---------------------------------------------------------------------------

typedef __attribute__((ext_vector_type(8))) short short8;
typedef __attribute__((ext_vector_type(4))) float f32x4;
typedef __attribute__((ext_vector_type(2))) float f32x2;

__device__ inline unsigned short f2bf(float f) {
  unsigned u = __float_as_uint(f);
  u += 0x7FFF + ((u >> 16) & 1);  // round-to-nearest-even
  return (unsigned short)(u >> 16);
}
__device__ inline float bf2f(unsigned short h) {
  return __uint_as_float(((unsigned)h) << 16);
}
__device__ inline float bf2fs(short h) { return bf2f((unsigned short)h); }

// ---- K1: per-chunk dual histogram (+ piggybacked mkW1 AND tobf16) ---------
__global__ __launch_bounds__(256) void sort_hist_mkW1_tobf16(
    const int* __restrict__ u_idx, const int* __restrict__ m_idx,
    int* __restrict__ hist_u, int* __restrict__ hist_m, int E, int nblk,
    const float* __restrict__ bases1, const float* __restrict__ coeff1,
    const float* __restrict__ root1,
    const float* __restrict__ bases2, const float* __restrict__ coeff2,
    float* __restrict__ Wcat1u, float* __restrict__ Wcat1m,
    float* __restrict__ wp2, float* __restrict__ wr2,
    const float* __restrict__ xu, unsigned short* __restrict__ xbu, int n4u,
    const float* __restrict__ xm, unsigned short* __restrict__ xbm, int n4m) {
  int t = threadIdx.x, blk = blockIdx.x;
  if (blk >= nblk + 16) {  // 512 trailing blocks: bf16 conversion
    int i = (blk - nblk - 16) * 256 + t;
    int stride = 512 * 256;
    int tot = n4u + n4m;
    for (int j = i; j < tot; j += stride) {
      float4 v = (j < n4u) ? reinterpret_cast<const float4*>(xu)[j]
                           : reinterpret_cast<const float4*>(xm)[j - n4u];
      ushort4 o;
      o.x = f2bf(v.x); o.y = f2bf(v.y); o.z = f2bf(v.z); o.w = f2bf(v.w);
      if (j < n4u) reinterpret_cast<ushort4*>(xbu)[j] = o;
      else reinterpret_cast<ushort4*>(xbm)[j - n4u] = o;
    }
    return;
  }
  if (blk >= nblk) {  // 16 blocks: mkW1
    int ij = (blk - nblk) * 256 + t;  // 0..4095
    float a0 = bases1[ij], a1 = bases1[4096 + ij], a2 = bases1[8192 + ij];
    Wcat1m[ij] = coeff1[0] * a0 + coeff1[1] * a1 + coeff1[2] * a2;  // W_pays1
    Wcat1u[ij] = coeff1[3] * a0 + coeff1[4] * a1 + coeff1[5] * a2;  // W_rev1
    float r = root1[ij];
    Wcat1m[4096 + ij] = r;
    Wcat1u[4096 + ij] = r;
    float c0 = bases2[ij], c1 = bases2[4096 + ij], c2 = bases2[8192 + ij];
    wp2[ij] = coeff2[0] * c0 + coeff2[1] * c1 + coeff2[2] * c2;
    wr2[ij] = coeff2[3] * c0 + coeff2[4] * c1 + coeff2[5] * c2;
    return;
  }
  __shared__ int hu[256], hm[256];
  hu[t] = 0; hm[t] = 0;
  __syncthreads();
  int base = blk * 2048 + t * 8;   // 8 contiguous edges per thread
  if (base + 8 <= E) {
    int4 ua = *reinterpret_cast<const int4*>(u_idx + base);
    int4 ub = *reinterpret_cast<const int4*>(u_idx + base + 4);
    int4 ma = *reinterpret_cast<const int4*>(m_idx + base);
    int4 mb = *reinterpret_cast<const int4*>(m_idx + base + 4);
    atomicAdd(&hu[ua.x >> 10], 1); atomicAdd(&hu[ua.y >> 10], 1);
    atomicAdd(&hu[ua.z >> 10], 1); atomicAdd(&hu[ua.w >> 10], 1);
    atomicAdd(&hu[ub.x >> 10], 1); atomicAdd(&hu[ub.y >> 10], 1);
    atomicAdd(&hu[ub.z >> 10], 1); atomicAdd(&hu[ub.w >> 10], 1);
    atomicAdd(&hm[ma.x >> 8], 1); atomicAdd(&hm[ma.y >> 8], 1);
    atomicAdd(&hm[ma.z >> 8], 1); atomicAdd(&hm[ma.w >> 8], 1);
    atomicAdd(&hm[mb.x >> 8], 1); atomicAdd(&hm[mb.y >> 8], 1);
    atomicAdd(&hm[mb.z >> 8], 1); atomicAdd(&hm[mb.w >> 8], 1);
  } else {
    for (int e = base; e < E; ++e) {
      atomicAdd(&hu[u_idx[e] >> 10], 1);
      atomicAdd(&hm[m_idx[e] >> 8], 1);
    }
  }
  __syncthreads();
  hist_u[t * nblk + blk] = hu[t];  // [bin][blk] layout
  hist_m[t * nblk + blk] = hm[t];
}

// ---- scanA for both hists (+ piggybacked mkW2) ----------------------------
__global__ __launch_bounds__(256) void scanA2_mkW2(
    int* __restrict__ hist_u, int* __restrict__ hist_m,
    int* __restrict__ part, int nhist, int sb,
    const float* __restrict__ wp2, const float* __restrict__ wr2,
    const float* __restrict__ root2, const float* __restrict__ w_mlp1,
    const float* __restrict__ b2, const float* __restrict__ b_mlp1,
    float* __restrict__ Wcat2u, float* __restrict__ Wcat2m,
    float* __restrict__ bu2, float* __restrict__ bm2) {
  int blk = blockIdx.x;
  if (blk >= 2 * sb) {  // 16 trailing blocks: mkW2
    int tid = (blk - 2 * sb) * 256 + threadIdx.x;  // 0..4095
    int i = tid >> 6, j = tid & 63;
    float au = 0.f, ru = 0.f, am = 0.f, rm = 0.f;
    for (int k = 0; k < 64; ++k) {
      float wa = w_mlp1[k * 64 + j];
      float wb = w_mlp1[(64 + k) * 64 + j];
      au += wr2[i * 64 + k] * wa;
      ru += root2[i * 64 + k] * wa;
      am += wp2[i * 64 + k] * wb;
      rm += root2[i * 64 + k] * wb;
    }
    Wcat2u[tid] = au; Wcat2u[4096 + tid] = ru;
    Wcat2m[tid] = am; Wcat2m[4096 + tid] = rm;
    if (i == 0) {
      float s1 = 0.f, s2 = 0.f;
      for (int k = 0; k < 64; ++k) {
        s1 += b2[k] * w_mlp1[k * 64 + j];
        s2 += b2[k] * w_mlp1[(64 + k) * 64 + j];
      }
      bu2[j] = s1;
      bm2[j] = s2 + b_mlp1[j];
    }
    return;
  }
  int* arr; int* prt;
  if (blk < sb) { arr = hist_u; prt = part; }
  else { arr = hist_m; prt = part + 256; blk -= sb; }
  __shared__ int s[256];
  int t = threadIdx.x;
  int base = blk * 2048 + t * 8;
  int v[8]; int sum = 0;
#pragma unroll
  for (int i = 0; i < 8; ++i) { int idx = base + i; v[i] = (idx < nhist) ? arr[idx] : 0; sum += v[i]; }
  s[t] = sum;
  __syncthreads();
  for (int ofs = 1; ofs < 256; ofs <<= 1) {
    int a = (t >= ofs) ? s[t - ofs] : 0;
    __syncthreads();
    s[t] += a;
    __syncthreads();
  }
  int run = s[t] - sum;
#pragma unroll
  for (int i = 0; i < 8; ++i) { int idx = base + i; if (idx < nhist) arr[idx] = run; run += v[i]; }
  if (t == 255) prt[blk] = s[255];
}

// ---- scanB for both partial arrays (+ piggybacked packW4) -----------------
__global__ __launch_bounds__(256) void scanB2_packW4(
    int* __restrict__ part, int NB,
    const float* __restrict__ s0, const float* __restrict__ s1,
    const float* __restrict__ s2, const float* __restrict__ s3,
    unsigned short* __restrict__ d0, unsigned short* __restrict__ d1,
    unsigned short* __restrict__ d2, unsigned short* __restrict__ d3) {
  int blk = blockIdx.x;
  if (blk >= 2) {  // 128 trailing blocks: packW4
    int gid = (blk - 2) * 256 + threadIdx.x;   // 0..32767
    int mat = gid >> 13;
    int tid = gid & 8191;
    int frag = tid >> 9;
    int nt = frag >> 2, ks = frag & 3;
    int lane = (tid >> 3) & 63;
    int i = tid & 7;
    int k = ks * 32 + (lane >> 4) * 8 + i;
    int col = nt * 16 + (lane & 15);
    const float* s = (mat == 0) ? s0 : (mat == 1) ? s1 : (mat == 2) ? s2 : s3;
    unsigned short* d = (mat == 0) ? d0 : (mat == 1) ? d1 : (mat == 2) ? d2 : d3;
    d[tid] = f2bf(s[k * 64 + col]);
    return;
  }
  int* prt = part + blk * 256;
  __shared__ int s[256];
  int t = threadIdx.x;
  int v = (t < NB) ? prt[t] : 0;
  s[t] = v;
  __syncthreads();
  for (int ofs = 1; ofs < 256; ofs <<= 1) {
    int a = (t >= ofs) ? s[t - ofs] : 0;
    __syncthreads();
    s[t] += a;
    __syncthreads();
  }
  if (t < NB) prt[t] = s[t] - v;
}

// ---- K3: partition into buckets, 4B packed entries, int4 edge reads -------
// scanC folded: cursor = hist[idx] + part[idx>>11].
__global__ __launch_bounds__(256) void sort_scatter1(
    const int* __restrict__ u_idx, const int* __restrict__ m_idx,
    const int* __restrict__ hist_u, const int* __restrict__ hist_m,
    const int* __restrict__ part,
    unsigned* __restrict__ stage_u, unsigned* __restrict__ stage_m,
    int E, int nblk) {
  __shared__ int cu[256], cm[256];
  int t = threadIdx.x, blk = blockIdx.x;
  int idx = t * nblk + blk;
  cu[t] = hist_u[idx] + part[idx >> 11];
  cm[t] = hist_m[idx] + part[256 + (idx >> 11)];
  __syncthreads();
  int base = blk * 2048 + t * 8;
  if (base + 8 <= E) {
    int4 ua = *reinterpret_cast<const int4*>(u_idx + base);
    int4 ub = *reinterpret_cast<const int4*>(u_idx + base + 4);
    int4 ma = *reinterpret_cast<const int4*>(m_idx + base);
    int4 mb = *reinterpret_cast<const int4*>(m_idx + base + 4);
    int us[8] = {ua.x, ua.y, ua.z, ua.w, ub.x, ub.y, ub.z, ub.w};
    int ms[8] = {ma.x, ma.y, ma.z, ma.w, mb.x, mb.y, mb.z, mb.w};
#pragma unroll
    for (int i = 0; i < 8; ++i) {
      int u = us[i], m = ms[i];
      int pu = atomicAdd(&cu[u >> 10], 1);
      stage_u[pu] = ((unsigned)(u & 1023) << 16) | (unsigned)m;   // m < 65536
      int pm = atomicAdd(&cm[m >> 8], 1);
      stage_m[pm] = ((unsigned)(m & 255) << 18) | (unsigned)u;    // u < 262144
    }
  } else {
    for (int e = base; e < E; ++e) {
      int u = u_idx[e], m = m_idx[e];
      int pu = atomicAdd(&cu[u >> 10], 1);
      stage_u[pu] = ((unsigned)(u & 1023) << 16) | (unsigned)m;
      int pm = atomicAdd(&cm[m >> 8], 1);
      stage_m[pm] = ((unsigned)(m & 255) << 18) | (unsigned)u;
    }
  }
}

// ---- K4: block-per-bucket low-digit counting sort -------------------------
template <int LOWBITS, int SHIFT, typename VT>
__device__ __forceinline__ void bucket_body(
    const unsigned* __restrict__ stage, const int* __restrict__ hs,
    const int* __restrict__ prt,
    VT* __restrict__ vals_out, int* __restrict__ off,
    int E, int N, int nblk, int b) {
  constexpr int NBIN = 1 << LOWBITS;
  constexpr int R = NBIN / 256;
  constexpr unsigned VMASK = (1u << SHIFT) - 1u;
  __shared__ int h[NBIN];
  __shared__ int s[256];
  int t = threadIdx.x;
  int i0 = b * nblk;
  int seg0 = hs[i0] + prt[i0 >> 11];
  int seg1 = E;
  if (b != 255) { int i1 = (b + 1) * nblk; seg1 = hs[i1] + prt[i1 >> 11]; }
#pragma unroll
  for (int r = 0; r < R; ++r) h[t * R + r] = 0;
  __syncthreads();
  for (int i = seg0 + t; i < seg1; i += 256)
    atomicAdd(&h[stage[i] >> SHIFT], 1);
  __syncthreads();
  int vals[R]; int loc = 0;
#pragma unroll
  for (int r = 0; r < R; ++r) { vals[r] = h[t * R + r]; loc += vals[r]; }
  s[t] = loc;
  __syncthreads();
  for (int ofs = 1; ofs < 256; ofs <<= 1) {
    int a = (t >= ofs) ? s[t - ofs] : 0;
    __syncthreads();
    s[t] += a;
    __syncthreads();
  }
  int run = seg0 + s[t] - loc;
#pragma unroll
  for (int r = 0; r < R; ++r) {
    int bin = t * R + r;
    h[bin] = run;
    int node = (b << LOWBITS) + bin;
    if (node <= N) off[node] = run;   // segment start; node==N -> E
    run += vals[r];
  }
  __syncthreads();
  for (int i = seg0 + t; i < seg1; i += 256) {
    unsigned v = stage[i];
    int pos = atomicAdd(&h[v >> SHIFT], 1);
    vals_out[pos] = (VT)(v & VMASK);
  }
}

__global__ __launch_bounds__(256) void sort_bucket2(
    const unsigned* __restrict__ stage_u, const int* __restrict__ hist_u,
    unsigned short* __restrict__ csr_u, int* __restrict__ off_u, int Nu,
    const unsigned* __restrict__ stage_m, const int* __restrict__ hist_m,
    int* __restrict__ csr_m, int* __restrict__ off_m, int Nm,
    const int* __restrict__ part, int E, int nblk) {
  if (blockIdx.x < 256)
    bucket_body<10, 16, unsigned short>(stage_u, hist_u, part, csr_u, off_u,
                                        E, Nu, nblk, blockIdx.x);
  else
    bucket_body<8, 18, int>(stage_m, hist_m, part + 256, csr_m, off_m,
                            E, Nm, nblk, blockIdx.x - 256);
}

// ---- fused segment-mean + MFMA transform + bias (+relu) -------------------
// wave owns 16 nodes; 8-lane subgroups (short8 = 16B/lane); unroll U over
// edges (U=8 m-side deg~40, U=4 u-side deg~10). A-tile [16][128] bf16 in
// LDS (passed in — one allocation shared by both template branches).
template <typename IT, int RELU, int U>
__device__ __forceinline__ void agg_body(
    unsigned short (*A)[16][128],
    const unsigned short* __restrict__ src,   // [Ns][64] bf16
    const unsigned short* __restrict__ selfF, // [N][64] bf16
    const int* __restrict__ off, const IT* __restrict__ csr,
    const unsigned short* __restrict__ Wp,    // packed B-frags
    const float* __restrict__ bias,           // [64]
    unsigned short* __restrict__ out, int N, int blk) {
  int t = threadIdx.x, wave = t >> 6, lane = t & 63;
  int nbase = (blk * 4 + wave) * 16;
  if (nbase >= N) return;  // wave-local tile, no cross-wave deps
  int fl = lane & 7, sub = lane >> 3;
  const short8* src8 = (const short8*)src;
  char* rowbase = (char*)&A[wave][0][0];
#pragma unroll 1
  for (int j = 0; j < 2; ++j) {
    int g = sub * 2 + j;
    int n = nbase + g;
    float ac[8] = {0.f, 0.f, 0.f, 0.f, 0.f, 0.f, 0.f, 0.f};
    float inv = 1.f;
    short8 sf8 = {0, 0, 0, 0, 0, 0, 0, 0};
    if (n < N) {
      int beg = off[n], end = off[n + 1], k = beg;
      for (; k + U <= end; k += U) {
        short8 r[U];
#pragma unroll
        for (int x = 0; x < U; ++x)
          r[x] = src8[(size_t)((int)csr[k + x]) * 8 + fl];
#pragma unroll
        for (int x = 0; x < U; ++x)
#pragma unroll
          for (int c = 0; c < 8; ++c) ac[c] += bf2fs(r[x][c]);
      }
      for (; k < end; ++k) {
        short8 r = src8[(size_t)((int)csr[k]) * 8 + fl];
#pragma unroll
        for (int c = 0; c < 8; ++c) ac[c] += bf2fs(r[c]);
      }
      inv = 1.f / fmaxf((float)(end - beg), 1.f);
      sf8 = ((const short8*)selfF)[(size_t)n * 8 + fl];
    }
    short8 ab;
#pragma unroll
    for (int c = 0; c < 8; ++c) ab[c] = (short)f2bf(ac[c] * inv);
    int swz = (g & 7) << 4;
    char* rp = rowbase + g * 256;
    *(short8*)(rp + ((fl * 16) ^ swz)) = ab;          // cols 0..63  (agg)
    *(short8*)(rp + ((128 + fl * 16) ^ swz)) = sf8;   // cols 64..127 (self)
  }
  // wave-local LDS write->read: compiler lgkmcnt ordering, no barrier
  int r = lane & 15, q = lane >> 4;
  int swzr = (r & 7) << 4;
  const char* arow = rowbase + r * 256;
  short8 af[4];
#pragma unroll
  for (int ks = 0; ks < 4; ++ks)
    af[ks] = *(const short8*)(arow + ((ks * 64 + q * 16) ^ swzr));
  const short8* wp8 = (const short8*)Wp;
#pragma unroll
  for (int nt = 0; nt < 4; ++nt) {
    float b = bias[nt * 16 + r];
    f32x4 acc = {b, b, b, b};
#pragma unroll
    for (int ks = 0; ks < 4; ++ks) {
      short8 bf = wp8[(nt * 4 + ks) * 64 + lane];
      acc = __builtin_amdgcn_mfma_f32_16x16x32_bf16(af[ks], bf, acc, 0, 0, 0);
    }
#pragma unroll
    for (int j = 0; j < 4; ++j) {
      int n = nbase + q * 4 + j;           // C row = (lane>>4)*4 + j
      if (n < N) {
        float v = acc[j];
        if (RELU) v = fmaxf(v, 0.f);
        out[(size_t)n * 64 + nt * 16 + r] = f2bf(v);  // C col = nt*16 + (lane&15)
      }
    }
  }
}

// Two independent agg passes fused; m-side (int csr, 4x work/node) FIRST
// (longest-job-first). ONE 16KB LDS tile shared by both branches.
template <int RELU>
__global__ __launch_bounds__(256) void agg_dual(
    const unsigned short* __restrict__ srcA, const unsigned short* __restrict__ selfA,
    const int* __restrict__ offA, const int* __restrict__ csrA,  // m-side
    const unsigned short* __restrict__ WpA, const float* __restrict__ biasA,
    unsigned short* __restrict__ outA, int NA, int gbA,
    const unsigned short* __restrict__ srcB, const unsigned short* __restrict__ selfB,
    const int* __restrict__ offB, const unsigned short* __restrict__ csrB,  // u-side
    const unsigned short* __restrict__ WpB, const float* __restrict__ biasB,
    unsigned short* __restrict__ outB, int NB) {
  __shared__ unsigned short A[4][16][128];    // 16 KB, shared by both branches
  int blk = blockIdx.x;
  if (blk < gbA)
    agg_body<int, RELU, 8>(A, srcA, selfA, offA, csrA, WpA, biasA, outA, NA, blk);
  else
    agg_body<unsigned short, RELU, 4>(A, srcB, selfB, offB, csrB, WpB, biasB, outB, NB, blk - gbA);
}

// ---- edge classifier, EDGE order, unroll x2, NT output stores -------------
__global__ __launch_bounds__(256) void edge_mlp(
    const unsigned short* __restrict__ pu, const unsigned short* __restrict__ pm,
    const int* __restrict__ u_idx, const int* __restrict__ m_idx,
    const float* __restrict__ w2, const float* __restrict__ bvec,
    float* __restrict__ out, int E) {
  int t = threadIdx.x;
  int lane = t & 63;
  int sub = lane >> 4;   // subgroup 0..3
  int fl = lane & 15;    // position in subgroup
  int f = fl * 4;        // features f..f+3
  int wid = (blockIdx.x * 256 + t) >> 6;
  int nw = (gridDim.x * 256) >> 6;
  float4 wA = reinterpret_cast<const float4*>(w2)[2 * fl];      // rows f, f+1
  float4 wB = reinterpret_cast<const float4*>(w2)[2 * fl + 1];  // rows f+2, f+3
  float ob0 = bvec[0], ob1 = bvec[1];
  int ngrp = (E + 7) >> 3;
  for (int g = wid; g < ngrp; g += nw) {
    int eA = g * 8 + sub, eB = eA + 4;
    bool vA = eA < E, vB = eB < E;
    int exA = vA ? eA : 0, exB = vB ? eB : 0;
    int uA = __builtin_nontemporal_load(&u_idx[exA]);
    int mA = __builtin_nontemporal_load(&m_idx[exA]);
    int uB = __builtin_nontemporal_load(&u_idx[exB]);
    int mB = __builtin_nontemporal_load(&m_idx[exB]);
    ushort4 a4A = *reinterpret_cast<const ushort4*>(&pu[(size_t)uA * 64 + f]);
    ushort4 b4A = *reinterpret_cast<const ushort4*>(&pm[(size_t)mA * 64 + f]);
    ushort4 a4B = *reinterpret_cast<const ushort4*>(&pu[(size_t)uB * 64 + f]);
    ushort4 b4B = *reinterpret_cast<const ushort4*>(&pm[(size_t)mB * 64 + f]);
    float v0 = fmaxf(bf2f(a4A.x) + bf2f(b4A.x), 0.f);
    float v1 = fmaxf(bf2f(a4A.y) + bf2f(b4A.y), 0.f);
    float v2 = fmaxf(bf2f(a4A.z) + bf2f(b4A.z), 0.f);
    float v3 = fmaxf(bf2f(a4A.w) + bf2f(b4A.w), 0.f);
    float p0 = v0 * wA.x + v1 * wA.z + v2 * wB.x + v3 * wB.z;
    float p1 = v0 * wA.y + v1 * wA.w + v2 * wB.y + v3 * wB.w;
    float w0 = fmaxf(bf2f(a4B.x) + bf2f(b4B.x), 0.f);
    float w1 = fmaxf(bf2f(a4B.y) + bf2f(b4B.y), 0.f);
    float w2v = fmaxf(bf2f(a4B.z) + bf2f(b4B.z), 0.f);
    float w3 = fmaxf(bf2f(a4B.w) + bf2f(b4B.w), 0.f);
    float q0 = w0 * wA.x + w1 * wA.z + w2v * wB.x + w3 * wB.z;
    float q1 = w0 * wA.y + w1 * wA.w + w2v * wB.y + w3 * wB.w;
#pragma unroll
    for (int o = 8; o; o >>= 1) {
      p0 += __shfl_xor(p0, o); p1 += __shfl_xor(p1, o);
      q0 += __shfl_xor(q0, o); q1 += __shfl_xor(q1, o);
    }
    if (fl == 0) {
      if (vA) {
        f32x2 oA = {p0 + ob0, p1 + ob1};
        __builtin_nontemporal_store(oA, (f32x2*)&out[(size_t)eA * 2]);
      }
      if (vB) {
        f32x2 oB = {q0 + ob0, q1 + ob1};
        __builtin_nontemporal_store(oB, (f32x2*)&out[(size_t)eB * 2]);
      }
    }
  }
}

extern "C" void kernel_launch(void* const* d_in, const int* in_sizes, int n_in,
                              void* d_out, int out_size, void* d_ws, size_t ws_size,
                              hipStream_t stream) {
  const float* x_user  = (const float*)d_in[0];
  const float* x_merch = (const float*)d_in[1];
  const float* bases1  = (const float*)d_in[2];
  const float* coeff1  = (const float*)d_in[3];
  const float* root1   = (const float*)d_in[4];
  const float* b1      = (const float*)d_in[5];
  const float* bases2  = (const float*)d_in[6];
  const float* coeff2  = (const float*)d_in[7];
  const float* root2   = (const float*)d_in[8];
  const float* b2      = (const float*)d_in[9];
  const float* w_mlp1  = (const float*)d_in[10];
  const float* b_mlp1  = (const float*)d_in[11];
  const float* w_mlp2  = (const float*)d_in[12];
  const float* b_mlp2  = (const float*)d_in[13];
  const int*   edge_ix = (const int*)d_in[14];

  const int Nu = in_sizes[0] / 64;
  const int Nm = in_sizes[1] / 64;
  const int E  = in_sizes[14] / 2;
  const int* u_idx = edge_ix;
  const int* m_idx = edge_ix + E;

  char* p = (char*)d_ws;
  auto alloc = [&](size_t bytes) -> char* {
    char* r = p;
    p += (bytes + 255) & ~(size_t)255;
    return r;
  };
  int* off_u = (int*)alloc((size_t)(Nu + 1) * 4);
  int* off_m = (int*)alloc((size_t)(Nm + 1) * 4);
  int* part  = (int*)alloc(512 * 4);
  unsigned short* csr_u = (unsigned short*)alloc((size_t)E * 2);  // merchant ids (16b)
  int* csr_m = (int*)alloc((size_t)E * 4);                        // user ids
  unsigned short* xb_u = (unsigned short*)alloc((size_t)Nu * 64 * 2);  // later pu
  unsigned short* xb_m = (unsigned short*)alloc((size_t)Nm * 64 * 2);  // later pm
  unsigned short* h_u  = (unsigned short*)alloc((size_t)Nu * 64 * 2);  // also stage alias
  unsigned short* h_m  = (unsigned short*)alloc((size_t)Nm * 64 * 2);  // also hist alias
  float* Wcat1u = (float*)alloc(8192 * 4);
  float* Wcat1m = (float*)alloc(8192 * 4);
  float* Wcat2u = (float*)alloc(8192 * 4);
  float* Wcat2m = (float*)alloc(8192 * 4);
  unsigned short* Wp1u = (unsigned short*)alloc(8192 * 2);
  unsigned short* Wp1m = (unsigned short*)alloc(8192 * 2);
  unsigned short* Wp2u = (unsigned short*)alloc(8192 * 2);
  unsigned short* Wp2m = (unsigned short*)alloc(8192 * 2);
  float* wp2 = (float*)alloc(4096 * 4);
  float* wr2 = (float*)alloc(4096 * 4);
  float* bu2 = (float*)alloc(64 * 4);
  float* bm2 = (float*)alloc(64 * 4);
  if ((size_t)(p - (char*)d_ws) > ws_size) return;

  const int nblk = (E + 2047) / 2048;
  const int nhist = 256 * nblk;
  const int sb = (nhist + 2047) / 2048;
  // aliases: stages live in h_u (25.6MB >= 16MB), hists in h_m (6.4MB >= 2MB).
  // lifetimes: sort_bucket2 (last stage/hist reader) precedes agg_dual<1>
  // (first writer of h_u/h_m) in stream order.
  unsigned* stage_u = (unsigned*)h_u;
  unsigned* stage_m = stage_u + E;
  int* hist_u = (int*)h_m;
  int* hist_m = hist_u + nhist;

  // ---- CSR build (bucket sort) with piggybacked weight prep + tobf16 ----
  sort_hist_mkW1_tobf16<<<nblk + 16 + 512, 256, 0, stream>>>(
      u_idx, m_idx, hist_u, hist_m, E, nblk,
      bases1, coeff1, root1, bases2, coeff2, Wcat1u, Wcat1m, wp2, wr2,
      x_user, xb_u, Nu * 16, x_merch, xb_m, Nm * 16);
  scanA2_mkW2<<<2 * sb + 16, 256, 0, stream>>>(
      hist_u, hist_m, part, nhist, sb,
      wp2, wr2, root2, w_mlp1, b2, b_mlp1, Wcat2u, Wcat2m, bu2, bm2);
  scanB2_packW4<<<130, 256, 0, stream>>>(
      part, sb, Wcat1u, Wcat1m, Wcat2u, Wcat2m, Wp1u, Wp1m, Wp2u, Wp2m);
  sort_scatter1<<<nblk, 256, 0, stream>>>(
      u_idx, m_idx, hist_u, hist_m, part, stage_u, stage_m, E, nblk);
  sort_bucket2<<<512, 256, 0, stream>>>(stage_u, hist_u, csr_u, off_u, Nu,
                                        stage_m, hist_m, csr_m, off_m, Nm,
                                        part, E, nblk);

  int gbu = (Nu + 63) / 64, gbm = (Nm + 63) / 64;
  // layer 1 (relu): m-agg (big user-table gathers) first, then u-agg
  agg_dual<1><<<gbm + gbu, 256, 0, stream>>>(
      xb_u, xb_m, off_m, csr_m, Wp1m, b1, h_m, Nm, gbm,
      xb_m, xb_u, off_u, csr_u, Wp1u, b1, h_u, Nu);
  // layer 2 fused with edge-MLP left matrix: pm (gathers h_u) first, then pu
  unsigned short* pm_buf = xb_m;
  unsigned short* pu_buf = xb_u;
  agg_dual<0><<<gbm + gbu, 256, 0, stream>>>(
      h_u, h_m, off_m, csr_m, Wp2m, bm2, pm_buf, Nm, gbm,
      h_m, h_u, off_u, csr_u, Wp2u, bu2, pu_buf, Nu);

  edge_mlp<<<2048, 256, 0, stream>>>(pu_buf, pm_buf, u_idx, m_idx,
                                     w_mlp2, b_mlp2, (float*)d_out, E);
}

// Round 13
// 323.941 us; speedup vs baseline: 1.0630x; 1.0630x over previous
//
#include <hip/hip_runtime.h>

// ---------------------------------------------------------------------------
// Hetero-SAGE edge classifier.
//  Round-13: revert R12's agg unroll-8 (VGPR 36->52 crossed an occupancy
//  cliff: 64%->39%, agg 83->94us — occupancy, not ILP, is the binding
//  resource for the fabric-bound gather). Keep R12's sort-chain wins:
//  tobf16 piggybacked on hist launch, int4 edge reads, NT edge_mlp stores.
//  __launch_bounds__(256,8) pins agg_dual to the 8-block/CU register budget.
// ---------------------------------------------------------------------------

typedef __attribute__((ext_vector_type(8))) short short8;
typedef __attribute__((ext_vector_type(4))) float f32x4;
typedef __attribute__((ext_vector_type(2))) float f32x2;

__device__ inline unsigned short f2bf(float f) {
  unsigned u = __float_as_uint(f);
  u += 0x7FFF + ((u >> 16) & 1);  // round-to-nearest-even
  return (unsigned short)(u >> 16);
}
__device__ inline float bf2f(unsigned short h) {
  return __uint_as_float(((unsigned)h) << 16);
}
__device__ inline float bf2fs(short h) { return bf2f((unsigned short)h); }

// ---- K1: per-chunk dual histogram (+ piggybacked mkW1 AND tobf16) ---------
__global__ __launch_bounds__(256) void sort_hist_mkW1_tobf16(
    const int* __restrict__ u_idx, const int* __restrict__ m_idx,
    int* __restrict__ hist_u, int* __restrict__ hist_m, int E, int nblk,
    const float* __restrict__ bases1, const float* __restrict__ coeff1,
    const float* __restrict__ root1,
    const float* __restrict__ bases2, const float* __restrict__ coeff2,
    float* __restrict__ Wcat1u, float* __restrict__ Wcat1m,
    float* __restrict__ wp2, float* __restrict__ wr2,
    const float* __restrict__ xu, unsigned short* __restrict__ xbu, int n4u,
    const float* __restrict__ xm, unsigned short* __restrict__ xbm, int n4m) {
  int t = threadIdx.x, blk = blockIdx.x;
  if (blk >= nblk + 16) {  // 512 trailing blocks: bf16 conversion
    int i = (blk - nblk - 16) * 256 + t;
    int stride = 512 * 256;
    int tot = n4u + n4m;
    for (int j = i; j < tot; j += stride) {
      float4 v = (j < n4u) ? reinterpret_cast<const float4*>(xu)[j]
                           : reinterpret_cast<const float4*>(xm)[j - n4u];
      ushort4 o;
      o.x = f2bf(v.x); o.y = f2bf(v.y); o.z = f2bf(v.z); o.w = f2bf(v.w);
      if (j < n4u) reinterpret_cast<ushort4*>(xbu)[j] = o;
      else reinterpret_cast<ushort4*>(xbm)[j - n4u] = o;
    }
    return;
  }
  if (blk >= nblk) {  // 16 blocks: mkW1
    int ij = (blk - nblk) * 256 + t;  // 0..4095
    float a0 = bases1[ij], a1 = bases1[4096 + ij], a2 = bases1[8192 + ij];
    Wcat1m[ij] = coeff1[0] * a0 + coeff1[1] * a1 + coeff1[2] * a2;  // W_pays1
    Wcat1u[ij] = coeff1[3] * a0 + coeff1[4] * a1 + coeff1[5] * a2;  // W_rev1
    float r = root1[ij];
    Wcat1m[4096 + ij] = r;
    Wcat1u[4096 + ij] = r;
    float c0 = bases2[ij], c1 = bases2[4096 + ij], c2 = bases2[8192 + ij];
    wp2[ij] = coeff2[0] * c0 + coeff2[1] * c1 + coeff2[2] * c2;
    wr2[ij] = coeff2[3] * c0 + coeff2[4] * c1 + coeff2[5] * c2;
    return;
  }
  __shared__ int hu[256], hm[256];
  hu[t] = 0; hm[t] = 0;
  __syncthreads();
  int base = blk * 2048 + t * 8;   // 8 contiguous edges per thread
  if (base + 8 <= E) {
    int4 ua = *reinterpret_cast<const int4*>(u_idx + base);
    int4 ub = *reinterpret_cast<const int4*>(u_idx + base + 4);
    int4 ma = *reinterpret_cast<const int4*>(m_idx + base);
    int4 mb = *reinterpret_cast<const int4*>(m_idx + base + 4);
    atomicAdd(&hu[ua.x >> 10], 1); atomicAdd(&hu[ua.y >> 10], 1);
    atomicAdd(&hu[ua.z >> 10], 1); atomicAdd(&hu[ua.w >> 10], 1);
    atomicAdd(&hu[ub.x >> 10], 1); atomicAdd(&hu[ub.y >> 10], 1);
    atomicAdd(&hu[ub.z >> 10], 1); atomicAdd(&hu[ub.w >> 10], 1);
    atomicAdd(&hm[ma.x >> 8], 1); atomicAdd(&hm[ma.y >> 8], 1);
    atomicAdd(&hm[ma.z >> 8], 1); atomicAdd(&hm[ma.w >> 8], 1);
    atomicAdd(&hm[mb.x >> 8], 1); atomicAdd(&hm[mb.y >> 8], 1);
    atomicAdd(&hm[mb.z >> 8], 1); atomicAdd(&hm[mb.w >> 8], 1);
  } else {
    for (int e = base; e < E; ++e) {
      atomicAdd(&hu[u_idx[e] >> 10], 1);
      atomicAdd(&hm[m_idx[e] >> 8], 1);
    }
  }
  __syncthreads();
  hist_u[t * nblk + blk] = hu[t];  // [bin][blk] layout
  hist_m[t * nblk + blk] = hm[t];
}

// ---- scanA for both hists (+ piggybacked mkW2) ----------------------------
__global__ __launch_bounds__(256) void scanA2_mkW2(
    int* __restrict__ hist_u, int* __restrict__ hist_m,
    int* __restrict__ part, int nhist, int sb,
    const float* __restrict__ wp2, const float* __restrict__ wr2,
    const float* __restrict__ root2, const float* __restrict__ w_mlp1,
    const float* __restrict__ b2, const float* __restrict__ b_mlp1,
    float* __restrict__ Wcat2u, float* __restrict__ Wcat2m,
    float* __restrict__ bu2, float* __restrict__ bm2) {
  int blk = blockIdx.x;
  if (blk >= 2 * sb) {  // 16 trailing blocks: mkW2
    int tid = (blk - 2 * sb) * 256 + threadIdx.x;  // 0..4095
    int i = tid >> 6, j = tid & 63;
    float au = 0.f, ru = 0.f, am = 0.f, rm = 0.f;
    for (int k = 0; k < 64; ++k) {
      float wa = w_mlp1[k * 64 + j];
      float wb = w_mlp1[(64 + k) * 64 + j];
      au += wr2[i * 64 + k] * wa;
      ru += root2[i * 64 + k] * wa;
      am += wp2[i * 64 + k] * wb;
      rm += root2[i * 64 + k] * wb;
    }
    Wcat2u[tid] = au; Wcat2u[4096 + tid] = ru;
    Wcat2m[tid] = am; Wcat2m[4096 + tid] = rm;
    if (i == 0) {
      float s1 = 0.f, s2 = 0.f;
      for (int k = 0; k < 64; ++k) {
        s1 += b2[k] * w_mlp1[k * 64 + j];
        s2 += b2[k] * w_mlp1[(64 + k) * 64 + j];
      }
      bu2[j] = s1;
      bm2[j] = s2 + b_mlp1[j];
    }
    return;
  }
  int* arr; int* prt;
  if (blk < sb) { arr = hist_u; prt = part; }
  else { arr = hist_m; prt = part + 256; blk -= sb; }
  __shared__ int s[256];
  int t = threadIdx.x;
  int base = blk * 2048 + t * 8;
  int v[8]; int sum = 0;
#pragma unroll
  for (int i = 0; i < 8; ++i) { int idx = base + i; v[i] = (idx < nhist) ? arr[idx] : 0; sum += v[i]; }
  s[t] = sum;
  __syncthreads();
  for (int ofs = 1; ofs < 256; ofs <<= 1) {
    int a = (t >= ofs) ? s[t - ofs] : 0;
    __syncthreads();
    s[t] += a;
    __syncthreads();
  }
  int run = s[t] - sum;
#pragma unroll
  for (int i = 0; i < 8; ++i) { int idx = base + i; if (idx < nhist) arr[idx] = run; run += v[i]; }
  if (t == 255) prt[blk] = s[255];
}

// ---- scanB for both partial arrays (+ piggybacked packW4) -----------------
__global__ __launch_bounds__(256) void scanB2_packW4(
    int* __restrict__ part, int NB,
    const float* __restrict__ s0, const float* __restrict__ s1,
    const float* __restrict__ s2, const float* __restrict__ s3,
    unsigned short* __restrict__ d0, unsigned short* __restrict__ d1,
    unsigned short* __restrict__ d2, unsigned short* __restrict__ d3) {
  int blk = blockIdx.x;
  if (blk >= 2) {  // 128 trailing blocks: packW4
    int gid = (blk - 2) * 256 + threadIdx.x;   // 0..32767
    int mat = gid >> 13;
    int tid = gid & 8191;
    int frag = tid >> 9;
    int nt = frag >> 2, ks = frag & 3;
    int lane = (tid >> 3) & 63;
    int i = tid & 7;
    int k = ks * 32 + (lane >> 4) * 8 + i;
    int col = nt * 16 + (lane & 15);
    const float* s = (mat == 0) ? s0 : (mat == 1) ? s1 : (mat == 2) ? s2 : s3;
    unsigned short* d = (mat == 0) ? d0 : (mat == 1) ? d1 : (mat == 2) ? d2 : d3;
    d[tid] = f2bf(s[k * 64 + col]);
    return;
  }
  int* prt = part + blk * 256;
  __shared__ int s[256];
  int t = threadIdx.x;
  int v = (t < NB) ? prt[t] : 0;
  s[t] = v;
  __syncthreads();
  for (int ofs = 1; ofs < 256; ofs <<= 1) {
    int a = (t >= ofs) ? s[t - ofs] : 0;
    __syncthreads();
    s[t] += a;
    __syncthreads();
  }
  if (t < NB) prt[t] = s[t] - v;
}

// ---- K3: partition into buckets, 4B packed entries, int4 edge reads -------
// scanC folded: cursor = hist[idx] + part[idx>>11].
__global__ __launch_bounds__(256) void sort_scatter1(
    const int* __restrict__ u_idx, const int* __restrict__ m_idx,
    const int* __restrict__ hist_u, const int* __restrict__ hist_m,
    const int* __restrict__ part,
    unsigned* __restrict__ stage_u, unsigned* __restrict__ stage_m,
    int E, int nblk) {
  __shared__ int cu[256], cm[256];
  int t = threadIdx.x, blk = blockIdx.x;
  int idx = t * nblk + blk;
  cu[t] = hist_u[idx] + part[idx >> 11];
  cm[t] = hist_m[idx] + part[256 + (idx >> 11)];
  __syncthreads();
  int base = blk * 2048 + t * 8;
  if (base + 8 <= E) {
    int4 ua = *reinterpret_cast<const int4*>(u_idx + base);
    int4 ub = *reinterpret_cast<const int4*>(u_idx + base + 4);
    int4 ma = *reinterpret_cast<const int4*>(m_idx + base);
    int4 mb = *reinterpret_cast<const int4*>(m_idx + base + 4);
    int us[8] = {ua.x, ua.y, ua.z, ua.w, ub.x, ub.y, ub.z, ub.w};
    int ms[8] = {ma.x, ma.y, ma.z, ma.w, mb.x, mb.y, mb.z, mb.w};
#pragma unroll
    for (int i = 0; i < 8; ++i) {
      int u = us[i], m = ms[i];
      int pu = atomicAdd(&cu[u >> 10], 1);
      stage_u[pu] = ((unsigned)(u & 1023) << 16) | (unsigned)m;   // m < 65536
      int pm = atomicAdd(&cm[m >> 8], 1);
      stage_m[pm] = ((unsigned)(m & 255) << 18) | (unsigned)u;    // u < 262144
    }
  } else {
    for (int e = base; e < E; ++e) {
      int u = u_idx[e], m = m_idx[e];
      int pu = atomicAdd(&cu[u >> 10], 1);
      stage_u[pu] = ((unsigned)(u & 1023) << 16) | (unsigned)m;
      int pm = atomicAdd(&cm[m >> 8], 1);
      stage_m[pm] = ((unsigned)(m & 255) << 18) | (unsigned)u;
    }
  }
}

// ---- K4: block-per-bucket low-digit counting sort -------------------------
template <int LOWBITS, int SHIFT, typename VT>
__device__ __forceinline__ void bucket_body(
    const unsigned* __restrict__ stage, const int* __restrict__ hs,
    const int* __restrict__ prt,
    VT* __restrict__ vals_out, int* __restrict__ off,
    int E, int N, int nblk, int b) {
  constexpr int NBIN = 1 << LOWBITS;
  constexpr int R = NBIN / 256;
  constexpr unsigned VMASK = (1u << SHIFT) - 1u;
  __shared__ int h[NBIN];
  __shared__ int s[256];
  int t = threadIdx.x;
  int i0 = b * nblk;
  int seg0 = hs[i0] + prt[i0 >> 11];
  int seg1 = E;
  if (b != 255) { int i1 = (b + 1) * nblk; seg1 = hs[i1] + prt[i1 >> 11]; }
#pragma unroll
  for (int r = 0; r < R; ++r) h[t * R + r] = 0;
  __syncthreads();
  for (int i = seg0 + t; i < seg1; i += 256)
    atomicAdd(&h[stage[i] >> SHIFT], 1);
  __syncthreads();
  int vals[R]; int loc = 0;
#pragma unroll
  for (int r = 0; r < R; ++r) { vals[r] = h[t * R + r]; loc += vals[r]; }
  s[t] = loc;
  __syncthreads();
  for (int ofs = 1; ofs < 256; ofs <<= 1) {
    int a = (t >= ofs) ? s[t - ofs] : 0;
    __syncthreads();
    s[t] += a;
    __syncthreads();
  }
  int run = seg0 + s[t] - loc;
#pragma unroll
  for (int r = 0; r < R; ++r) {
    int bin = t * R + r;
    h[bin] = run;
    int node = (b << LOWBITS) + bin;
    if (node <= N) off[node] = run;   // segment start; node==N -> E
    run += vals[r];
  }
  __syncthreads();
  for (int i = seg0 + t; i < seg1; i += 256) {
    unsigned v = stage[i];
    int pos = atomicAdd(&h[v >> SHIFT], 1);
    vals_out[pos] = (VT)(v & VMASK);
  }
}

__global__ __launch_bounds__(256) void sort_bucket2(
    const unsigned* __restrict__ stage_u, const int* __restrict__ hist_u,
    unsigned short* __restrict__ csr_u, int* __restrict__ off_u, int Nu,
    const unsigned* __restrict__ stage_m, const int* __restrict__ hist_m,
    int* __restrict__ csr_m, int* __restrict__ off_m, int Nm,
    const int* __restrict__ part, int E, int nblk) {
  if (blockIdx.x < 256)
    bucket_body<10, 16, unsigned short>(stage_u, hist_u, part, csr_u, off_u,
                                        E, Nu, nblk, blockIdx.x);
  else
    bucket_body<8, 18, int>(stage_m, hist_m, part + 256, csr_m, off_m,
                            E, Nm, nblk, blockIdx.x - 256);
}

// ---- fused segment-mean + MFMA transform + bias (+relu) -------------------
// wave owns 16 nodes; 8-lane subgroups (short8 = 16B/lane), 2 nodes/subgroup
// x unroll-4 -> 32 outstanding row-gathers/wave (R11 form: 36 VGPR, 64% occ;
// U=8 regressed via register-pressure occupancy cliff, R12).
template <typename IT, int RELU>
__device__ __forceinline__ void agg_body(
    unsigned short (*A)[16][128],
    const unsigned short* __restrict__ src,   // [Ns][64] bf16
    const unsigned short* __restrict__ selfF, // [N][64] bf16
    const int* __restrict__ off, const IT* __restrict__ csr,
    const unsigned short* __restrict__ Wp,    // packed B-frags
    const float* __restrict__ bias,           // [64]
    unsigned short* __restrict__ out, int N, int blk) {
  int t = threadIdx.x, wave = t >> 6, lane = t & 63;
  int nbase = (blk * 4 + wave) * 16;
  if (nbase >= N) return;  // wave-local tile, no cross-wave deps
  int fl = lane & 7, sub = lane >> 3;
  const short8* src8 = (const short8*)src;
  char* rowbase = (char*)&A[wave][0][0];
#pragma unroll 1
  for (int j = 0; j < 2; ++j) {
    int g = sub * 2 + j;
    int n = nbase + g;
    float ac[8] = {0.f, 0.f, 0.f, 0.f, 0.f, 0.f, 0.f, 0.f};
    float inv = 1.f;
    short8 sf8 = {0, 0, 0, 0, 0, 0, 0, 0};
    if (n < N) {
      int beg = off[n], end = off[n + 1], k = beg;
      for (; k + 4 <= end; k += 4) {
        int s0 = (int)csr[k], s1 = (int)csr[k + 1];
        int s2 = (int)csr[k + 2], s3 = (int)csr[k + 3];
        short8 r0 = src8[(size_t)s0 * 8 + fl];
        short8 r1 = src8[(size_t)s1 * 8 + fl];
        short8 r2 = src8[(size_t)s2 * 8 + fl];
        short8 r3 = src8[(size_t)s3 * 8 + fl];
#pragma unroll
        for (int c = 0; c < 8; ++c)
          ac[c] += (bf2fs(r0[c]) + bf2fs(r1[c])) + (bf2fs(r2[c]) + bf2fs(r3[c]));
      }
      for (; k < end; ++k) {
        short8 r = src8[(size_t)((int)csr[k]) * 8 + fl];
#pragma unroll
        for (int c = 0; c < 8; ++c) ac[c] += bf2fs(r[c]);
      }
      inv = 1.f / fmaxf((float)(end - beg), 1.f);
      sf8 = ((const short8*)selfF)[(size_t)n * 8 + fl];
    }
    short8 ab;
#pragma unroll
    for (int c = 0; c < 8; ++c) ab[c] = (short)f2bf(ac[c] * inv);
    int swz = (g & 7) << 4;
    char* rp = rowbase + g * 256;
    *(short8*)(rp + ((fl * 16) ^ swz)) = ab;          // cols 0..63  (agg)
    *(short8*)(rp + ((128 + fl * 16) ^ swz)) = sf8;   // cols 64..127 (self)
  }
  // wave-local LDS write->read: compiler lgkmcnt ordering, no barrier
  int r = lane & 15, q = lane >> 4;
  int swzr = (r & 7) << 4;
  const char* arow = rowbase + r * 256;
  short8 af[4];
#pragma unroll
  for (int ks = 0; ks < 4; ++ks)
    af[ks] = *(const short8*)(arow + ((ks * 64 + q * 16) ^ swzr));
  const short8* wp8 = (const short8*)Wp;
#pragma unroll
  for (int nt = 0; nt < 4; ++nt) {
    float b = bias[nt * 16 + r];
    f32x4 acc = {b, b, b, b};
#pragma unroll
    for (int ks = 0; ks < 4; ++ks) {
      short8 bf = wp8[(nt * 4 + ks) * 64 + lane];
      acc = __builtin_amdgcn_mfma_f32_16x16x32_bf16(af[ks], bf, acc, 0, 0, 0);
    }
#pragma unroll
    for (int j = 0; j < 4; ++j) {
      int n = nbase + q * 4 + j;           // C row = (lane>>4)*4 + j
      if (n < N) {
        float v = acc[j];
        if (RELU) v = fmaxf(v, 0.f);
        out[(size_t)n * 64 + nt * 16 + r] = f2bf(v);  // C col = nt*16 + (lane&15)
      }
    }
  }
}

// Two independent agg passes fused; m-side (int csr, 4x work/node) FIRST
// (longest-job-first). ONE 16KB LDS tile; 8-block/CU register budget pinned.
template <int RELU>
__global__ __launch_bounds__(256, 8) void agg_dual(
    const unsigned short* __restrict__ srcA, const unsigned short* __restrict__ selfA,
    const int* __restrict__ offA, const int* __restrict__ csrA,  // m-side
    const unsigned short* __restrict__ WpA, const float* __restrict__ biasA,
    unsigned short* __restrict__ outA, int NA, int gbA,
    const unsigned short* __restrict__ srcB, const unsigned short* __restrict__ selfB,
    const int* __restrict__ offB, const unsigned short* __restrict__ csrB,  // u-side
    const unsigned short* __restrict__ WpB, const float* __restrict__ biasB,
    unsigned short* __restrict__ outB, int NB) {
  __shared__ unsigned short A[4][16][128];    // 16 KB, shared by both branches
  int blk = blockIdx.x;
  if (blk < gbA)
    agg_body<int, RELU>(A, srcA, selfA, offA, csrA, WpA, biasA, outA, NA, blk);
  else
    agg_body<unsigned short, RELU>(A, srcB, selfB, offB, csrB, WpB, biasB, outB, NB, blk - gbA);
}

// ---- edge classifier, EDGE order, unroll x2, NT output stores -------------
__global__ __launch_bounds__(256) void edge_mlp(
    const unsigned short* __restrict__ pu, const unsigned short* __restrict__ pm,
    const int* __restrict__ u_idx, const int* __restrict__ m_idx,
    const float* __restrict__ w2, const float* __restrict__ bvec,
    float* __restrict__ out, int E) {
  int t = threadIdx.x;
  int lane = t & 63;
  int sub = lane >> 4;   // subgroup 0..3
  int fl = lane & 15;    // position in subgroup
  int f = fl * 4;        // features f..f+3
  int wid = (blockIdx.x * 256 + t) >> 6;
  int nw = (gridDim.x * 256) >> 6;
  float4 wA = reinterpret_cast<const float4*>(w2)[2 * fl];      // rows f, f+1
  float4 wB = reinterpret_cast<const float4*>(w2)[2 * fl + 1];  // rows f+2, f+3
  float ob0 = bvec[0], ob1 = bvec[1];
  int ngrp = (E + 7) >> 3;
  for (int g = wid; g < ngrp; g += nw) {
    int eA = g * 8 + sub, eB = eA + 4;
    bool vA = eA < E, vB = eB < E;
    int exA = vA ? eA : 0, exB = vB ? eB : 0;
    int uA = __builtin_nontemporal_load(&u_idx[exA]);
    int mA = __builtin_nontemporal_load(&m_idx[exA]);
    int uB = __builtin_nontemporal_load(&u_idx[exB]);
    int mB = __builtin_nontemporal_load(&m_idx[exB]);
    ushort4 a4A = *reinterpret_cast<const ushort4*>(&pu[(size_t)uA * 64 + f]);
    ushort4 b4A = *reinterpret_cast<const ushort4*>(&pm[(size_t)mA * 64 + f]);
    ushort4 a4B = *reinterpret_cast<const ushort4*>(&pu[(size_t)uB * 64 + f]);
    ushort4 b4B = *reinterpret_cast<const ushort4*>(&pm[(size_t)mB * 64 + f]);
    float v0 = fmaxf(bf2f(a4A.x) + bf2f(b4A.x), 0.f);
    float v1 = fmaxf(bf2f(a4A.y) + bf2f(b4A.y), 0.f);
    float v2 = fmaxf(bf2f(a4A.z) + bf2f(b4A.z), 0.f);
    float v3 = fmaxf(bf2f(a4A.w) + bf2f(b4A.w), 0.f);
    float p0 = v0 * wA.x + v1 * wA.z + v2 * wB.x + v3 * wB.z;
    float p1 = v0 * wA.y + v1 * wA.w + v2 * wB.y + v3 * wB.w;
    float w0 = fmaxf(bf2f(a4B.x) + bf2f(b4B.x), 0.f);
    float w1 = fmaxf(bf2f(a4B.y) + bf2f(b4B.y), 0.f);
    float w2v = fmaxf(bf2f(a4B.z) + bf2f(b4B.z), 0.f);
    float w3 = fmaxf(bf2f(a4B.w) + bf2f(b4B.w), 0.f);
    float q0 = w0 * wA.x + w1 * wA.z + w2v * wB.x + w3 * wB.z;
    float q1 = w0 * wA.y + w1 * wA.w + w2v * wB.y + w3 * wB.w;
#pragma unroll
    for (int o = 8; o; o >>= 1) {
      p0 += __shfl_xor(p0, o); p1 += __shfl_xor(p1, o);
      q0 += __shfl_xor(q0, o); q1 += __shfl_xor(q1, o);
    }
    if (fl == 0) {
      if (vA) {
        f32x2 oA = {p0 + ob0, p1 + ob1};
        __builtin_nontemporal_store(oA, (f32x2*)&out[(size_t)eA * 2]);
      }
      if (vB) {
        f32x2 oB = {q0 + ob0, q1 + ob1};
        __builtin_nontemporal_store(oB, (f32x2*)&out[(size_t)eB * 2]);
      }
    }
  }
}

extern "C" void kernel_launch(void* const* d_in, const int* in_sizes, int n_in,
                              void* d_out, int out_size, void* d_ws, size_t ws_size,
                              hipStream_t stream) {
  const float* x_user  = (const float*)d_in[0];
  const float* x_merch = (const float*)d_in[1];
  const float* bases1  = (const float*)d_in[2];
  const float* coeff1  = (const float*)d_in[3];
  const float* root1   = (const float*)d_in[4];
  const float* b1      = (const float*)d_in[5];
  const float* bases2  = (const float*)d_in[6];
  const float* coeff2  = (const float*)d_in[7];
  const float* root2   = (const float*)d_in[8];
  const float* b2      = (const float*)d_in[9];
  const float* w_mlp1  = (const float*)d_in[10];
  const float* b_mlp1  = (const float*)d_in[11];
  const float* w_mlp2  = (const float*)d_in[12];
  const float* b_mlp2  = (const float*)d_in[13];
  const int*   edge_ix = (const int*)d_in[14];

  const int Nu = in_sizes[0] / 64;
  const int Nm = in_sizes[1] / 64;
  const int E  = in_sizes[14] / 2;
  const int* u_idx = edge_ix;
  const int* m_idx = edge_ix + E;

  char* p = (char*)d_ws;
  auto alloc = [&](size_t bytes) -> char* {
    char* r = p;
    p += (bytes + 255) & ~(size_t)255;
    return r;
  };
  int* off_u = (int*)alloc((size_t)(Nu + 1) * 4);
  int* off_m = (int*)alloc((size_t)(Nm + 1) * 4);
  int* part  = (int*)alloc(512 * 4);
  unsigned short* csr_u = (unsigned short*)alloc((size_t)E * 2);  // merchant ids (16b)
  int* csr_m = (int*)alloc((size_t)E * 4);                        // user ids
  unsigned short* xb_u = (unsigned short*)alloc((size_t)Nu * 64 * 2);  // later pu
  unsigned short* xb_m = (unsigned short*)alloc((size_t)Nm * 64 * 2);  // later pm
  unsigned short* h_u  = (unsigned short*)alloc((size_t)Nu * 64 * 2);  // also stage alias
  unsigned short* h_m  = (unsigned short*)alloc((size_t)Nm * 64 * 2);  // also hist alias
  float* Wcat1u = (float*)alloc(8192 * 4);
  float* Wcat1m = (float*)alloc(8192 * 4);
  float* Wcat2u = (float*)alloc(8192 * 4);
  float* Wcat2m = (float*)alloc(8192 * 4);
  unsigned short* Wp1u = (unsigned short*)alloc(8192 * 2);
  unsigned short* Wp1m = (unsigned short*)alloc(8192 * 2);
  unsigned short* Wp2u = (unsigned short*)alloc(8192 * 2);
  unsigned short* Wp2m = (unsigned short*)alloc(8192 * 2);
  float* wp2 = (float*)alloc(4096 * 4);
  float* wr2 = (float*)alloc(4096 * 4);
  float* bu2 = (float*)alloc(64 * 4);
  float* bm2 = (float*)alloc(64 * 4);
  if ((size_t)(p - (char*)d_ws) > ws_size) return;

  const int nblk = (E + 2047) / 2048;
  const int nhist = 256 * nblk;
  const int sb = (nhist + 2047) / 2048;
  // aliases: stages live in h_u (25.6MB >= 16MB), hists in h_m (6.4MB >= 2MB).
  // lifetimes: sort_bucket2 (last stage/hist reader) precedes agg_dual<1>
  // (first writer of h_u/h_m) in stream order.
  unsigned* stage_u = (unsigned*)h_u;
  unsigned* stage_m = stage_u + E;
  int* hist_u = (int*)h_m;
  int* hist_m = hist_u + nhist;

  // ---- CSR build (bucket sort) with piggybacked weight prep + tobf16 ----
  sort_hist_mkW1_tobf16<<<nblk + 16 + 512, 256, 0, stream>>>(
      u_idx, m_idx, hist_u, hist_m, E, nblk,
      bases1, coeff1, root1, bases2, coeff2, Wcat1u, Wcat1m, wp2, wr2,
      x_user, xb_u, Nu * 16, x_merch, xb_m, Nm * 16);
  scanA2_mkW2<<<2 * sb + 16, 256, 0, stream>>>(
      hist_u, hist_m, part, nhist, sb,
      wp2, wr2, root2, w_mlp1, b2, b_mlp1, Wcat2u, Wcat2m, bu2, bm2);
  scanB2_packW4<<<130, 256, 0, stream>>>(
      part, sb, Wcat1u, Wcat1m, Wcat2u, Wcat2m, Wp1u, Wp1m, Wp2u, Wp2m);
  sort_scatter1<<<nblk, 256, 0, stream>>>(
      u_idx, m_idx, hist_u, hist_m, part, stage_u, stage_m, E, nblk);
  sort_bucket2<<<512, 256, 0, stream>>>(stage_u, hist_u, csr_u, off_u, Nu,
                                        stage_m, hist_m, csr_m, off_m, Nm,
                                        part, E, nblk);

  int gbu = (Nu + 63) / 64, gbm = (Nm + 63) / 64;
  // layer 1 (relu): m-agg (big user-table gathers) first, then u-agg
  agg_dual<1><<<gbm + gbu, 256, 0, stream>>>(
      xb_u, xb_m, off_m, csr_m, Wp1m, b1, h_m, Nm, gbm,
      xb_m, xb_u, off_u, csr_u, Wp1u, b1, h_u, Nu);
  // layer 2 fused with edge-MLP left matrix: pm (gathers h_u) first, then pu
  unsigned short* pm_buf = xb_m;
  unsigned short* pu_buf = xb_u;
  agg_dual<0><<<gbm + gbu, 256, 0, stream>>>(
      h_u, h_m, off_m, csr_m, Wp2m, bm2, pm_buf, Nm, gbm,
      h_m, h_u, off_u, csr_u, Wp2u, bu2, pu_buf, Nu);

  edge_mlp<<<2048, 256, 0, stream>>>(pu_buf, pm_buf, u_idx, m_idx,
                                     w_mlp2, b_mlp2, (float*)d_out, E);
}